// Round 14
// baseline (258.983 us; speedup 1.0000x reference)
//
#include <hip/hip_runtime.h>

// B=4, S=2048, D_MODEL=1024, H=16, DK=64.  M = B*S = 8192.
// cvt weights (Wcat) -> cvt acts -> all GEMMs on gemmP: 128^2 tile, BK=32,
// 3-slot LDS ring (48KB -> 3 blocks/CU), counted vmcnt(4) (no in-loop drain)
// -> causal flash attention (round-10 proven) -> output GEMM (gemmP MODE 2).

typedef __bf16 bf16;
typedef bf16 bf16x8 __attribute__((ext_vector_type(8)));
typedef float f32x4 __attribute__((ext_vector_type(4)));
typedef unsigned short u16;
typedef unsigned int u32;
typedef u16 u16x8 __attribute__((ext_vector_type(8)));
typedef u16 u16x4 __attribute__((ext_vector_type(4)));

#define DEVI static __device__ __forceinline__

DEVI u16 f2b(float f) {                    // f32 -> bf16 bits, RNE
  union { float f; u32 u; } v; v.f = f;
  u32 r = v.u + 0x7FFFu + ((v.u >> 16) & 1u);
  return (u16)(r >> 16);
}
DEVI f32x4 mfma16(bf16x8 a, bf16x8 b, f32x4 c) {
  return __builtin_amdgcn_mfma_f32_16x16x32_bf16(a, b, c, 0, 0, 0);
}
DEVI void gload16(const void* g, void* l) {
  __builtin_amdgcn_global_load_lds(
      (const __attribute__((address_space(1))) void*)g,
      (__attribute__((address_space(3))) void*)l, 16, 0, 0);
}
DEVI u32 cvtpk(float lo, float hi) {       // bf16 pair, RNE
  u32 r;
  asm("v_cvt_pk_bf16_f32 %0, %1, %2" : "=v"(r) : "v"(lo), "v"(hi));
  return r;
}
DEVI void pswap(u32& a, u32& b) {          // a' = [a.lo|b.lo], b' = [a.hi|b.hi]
  asm("v_permlane32_swap_b32 %0, %1" : "+v"(a), "+v"(b));
}

// ---------------------------------------------------------------------------
// Wcat build: per pair (w1,w2) -> [2048,1024] bf16; tile-row t7 of each
// 128-row block maps gate g=(t7>>4)&1, col (t7>>5)*16+(t7&15).
struct P6 { const float* p[6]; };

__global__ void cvt_wpair(P6 in, u16* __restrict__ out) {
  const int pair = blockIdx.y;
  const float* w1 = in.p[2 * pair];
  const float* w2 = in.p[2 * pair + 1];
  u16* dst = out + (size_t)pair * 2097152;
  const int i = blockIdx.x * 256 + threadIdx.x;   // grid.x = 1024
  const int v = i >> 7;                           // Wcat row 0..2047
  const int k0 = (i & 127) << 3;
  const int t7 = v & 127;
  const int g = (t7 >> 4) & 1;
  const int c = (v >> 7) * 64 + ((t7 >> 5) << 4) + (t7 & 15);
  const float* src = (g ? w2 : w1) + (size_t)c * 1024 + k0;
  const f32x4 a = *(const f32x4*)src;
  const f32x4 b = *(const f32x4*)(src + 4);
  u16x8 wv;
#pragma unroll
  for (int j = 0; j < 4; ++j) { wv[j] = f2b(a[j]); wv[4 + j] = f2b(b[j]); }
  *(u16x8*)(dst + (size_t)v * 1024 + k0) = wv;
}

// f32 -> bf16, 8 elems/thread; grid.y selects (s0,d0) or (s1,d1).
__global__ void cvt_x(const float* __restrict__ s0, u16* __restrict__ d0,
                      const float* __restrict__ s1, u16* __restrict__ d1) {
  const float* src = blockIdx.y ? s1 : s0;
  u16* dst = blockIdx.y ? d1 : d0;
  const int i = blockIdx.x * 256 + threadIdx.x;
  const f32x4 a = ((const f32x4*)src)[i * 2];
  const f32x4 b = ((const f32x4*)src)[i * 2 + 1];
  u16x8 w;
#pragma unroll
  for (int j = 0; j < 4; ++j) { w[j] = f2b(a[j]); w[4 + j] = f2b(b[j]); }
  ((u16x8*)dst)[i] = w;
}

struct GArgs {
  const u16* A; const u16* W;
  const float* b1; const float* b2;
  void* out; float scale;
};

// ---------------------------------------------------------------------------
// gemmP: 128x128 tile, BK=32, 256 thr (4 waves 2x2 of 64x64), 3-slot LDS
// ring (48 KB -> 3 blocks/CU; unsynchronized blocks give cross-block
// MFMA/LDS overlap), counted vmcnt(4): tile t+1 landed, t+2 in flight --
// no vmcnt(0) drain inside the K-loop.  Bank swizzle: chunk ^= (row>>1)&3
// (measured conflict-free in round 13).
// Ring invariants (verified round 13): stage(t+2) -> slot (t+2)%3, whose
// last reader (tile t-1) finished before the barrier ending iter t-1;
// per-wave vmcnt(4) before each barrier makes its own stage(t+1) LDS
// writes visible block-wide after the barrier.
// MODE 0: dual-gate swiglu -> Q/K [B,H,S,64]; MODE 1: swiglu -> V^T;
// MODE 2: plain + bias -> f32.  DUAL: blocks >= 1024 use g1.
template<int MODE, bool DUAL>
__global__ __launch_bounds__(256, 2) void gemmP(GArgs g0, GArgs g1)
{
  __shared__ char smem[49152];                 // 3 x (As 8K | Bs 8K)
  const int fl = blockIdx.x;
  const GArgs g = (DUAL && fl >= 1024) ? g1 : g0;
  const int local = DUAL ? (fl & 1023) : fl;
  const int t = threadIdx.x;
  const int lane = t & 63, wid = t >> 6;
  const int lg = lane >> 4, lc = lane & 15;
  const int wr = (wid >> 1) * 64, wc = (wid & 1) * 64;
  constexpr int NXB = (MODE == 2) ? 8 : 16;    // N/128 strips
  const int xcd = local & 7, w8 = local >> 3;
  const int m0 = (xcd * 8 + w8 / NXB) * 128;   // bijective onto 64 m-panels
  const int bx = w8 % NXB;
  const int K = 1024;
  const int sr16 = lane >> 2;                  // staging row within 16-row chunk
  const int sc = lane & 3;                     // staging 16B chunk in 64B row

  const f32x4 fz = {0.f, 0.f, 0.f, 0.f};
  f32x4 acc[4][4];
#pragma unroll
  for (int i = 0; i < 4; ++i)
#pragma unroll
    for (int j = 0; j < 4; ++j) acc[i][j] = fz;

  auto STAGE = [&](int slot, int kt) {         // 4 loads/thread/K-tile
    const int k0 = kt << 5;
    char* As = smem + slot * 16384;
    char* Bs = As + 8192;
#pragma unroll
    for (int p = 0; p < 2; ++p) {
      const int rb = (wid * 2 + p) * 16;       // wave-uniform 16-row chunk
      const int row = rb + sr16;
      const int ce = (sc ^ ((row >> 1) & 3)) << 3;   // inv-swizzled src col
      gload16(g.A + (size_t)(m0 + row) * K + k0 + ce, As + rb * 64);
      gload16(g.W + (size_t)(bx * 128 + row) * K + k0 + ce, Bs + rb * 64);
    }
  };

  auto COMPUTE = [&](int slot) {
    const char* As = smem + slot * 16384;
    const char* Bs = As + 8192;
    bf16x8 af[4], bfr[4];
#pragma unroll
    for (int mf = 0; mf < 4; ++mf) {
      const int r = wr + mf * 16 + lc;
      af[mf] = *(const bf16x8*)(As + r * 64 + ((lg ^ ((r >> 1) & 3)) << 4));
    }
#pragma unroll
    for (int nf = 0; nf < 4; ++nf) {
      const int r = wc + nf * 16 + lc;
      bfr[nf] = *(const bf16x8*)(Bs + r * 64 + ((lg ^ ((r >> 1) & 3)) << 4));
    }
    __builtin_amdgcn_s_setprio(1);
#pragma unroll
    for (int mf = 0; mf < 4; ++mf)
#pragma unroll
      for (int nf = 0; nf < 4; ++nf)
        acc[mf][nf] = mfma16(af[mf], bfr[nf], acc[mf][nf]);
    __builtin_amdgcn_s_setprio(0);
  };

  // 3-ring pipelined K-loop, 32 tiles of BK=32.
  STAGE(0, 0);
  STAGE(1, 1);
  asm volatile("s_waitcnt vmcnt(4)" ::: "memory");   // tile 0 landed
  __builtin_amdgcn_s_barrier();
  for (int kt = 0; kt < 30; ++kt) {
    STAGE((kt + 2) % 3, kt + 2);
    COMPUTE(kt % 3);
    asm volatile("s_waitcnt vmcnt(4)" ::: "memory"); // tile kt+1 landed
    __builtin_amdgcn_s_barrier();
  }
  COMPUTE(0);                                        // tile 30
  asm volatile("s_waitcnt vmcnt(0)" ::: "memory");   // tile 31 landed
  __builtin_amdgcn_s_barrier();
  COMPUTE(1);                                        // tile 31

  // ---- epilogue (verbatim round-10 mappings) ----
  if constexpr (MODE == 2) {
    float* Co = (float*)g.out;
#pragma unroll
    for (int mf = 0; mf < 4; ++mf)
#pragma unroll
      for (int nf = 0; nf < 4; ++nf) {
        const int r0 = m0 + wr + mf * 16 + (lg << 2);
        const int C = bx * 128 + wc + nf * 16 + lc;
        const float bv = g.b1[C];
#pragma unroll
        for (int j = 0; j < 4; ++j)
          Co[(size_t)(r0 + j) * 1024 + C] = acc[mf][nf][j] + bv;
      }
  } else {
    u16* Co = (u16*)g.out;
#pragma unroll
    for (int mf = 0; mf < 4; ++mf) {
      const int r0 = m0 + wr + mf * 16 + (lg << 2);
#pragma unroll
      for (int p = 0; p < 2; ++p) {            // acc pairs (2p, 2p+1) = (G1,G2)
        const int C = bx * 64 + (wid & 1) * 32 + p * 16 + lc;
        const float b1v = g.b1[C], b2v = g.b2[C];
        const int h = C >> 6, d = C & 63;
        if constexpr (MODE == 0) {
#pragma unroll
          for (int j = 0; j < 4; ++j) {
            const int r = r0 + j;
            const float x = acc[mf][2 * p][j] + b1v;
            const float y = acc[mf][2 * p + 1][j] + b2v;
            const float vv = (x / (1.f + __expf(-x))) * y * g.scale;
            const int bb = r >> 11, s = r & 2047;
            Co[((size_t)(bb * 16 + h) * 2048 + s) * 64 + d] = f2b(vv);
          }
        } else {
          u16x4 wv;
#pragma unroll
          for (int j = 0; j < 4; ++j) {
            const float x = acc[mf][2 * p][j] + b1v;
            const float y = acc[mf][2 * p + 1][j] + b2v;
            wv[j] = f2b((x / (1.f + __expf(-x))) * y);
          }
          const int bb = r0 >> 11, s0 = r0 & 2047;   // r0 % 4 == 0
          *(u16x4*)(Co + ((size_t)(bb * 16 + h) * 64 + d) * 2048 + s0) = wv;
        }
      }
    }
  }
}

// ---------------------------------------------------------------------------
// Causal flash attention (round-10 proven).  LDS-staged K/V (dbuf
// global_load_lds, 1 barrier/tile), 4 waves x 32 q/wave = 128 q/block,
// 1024-block LPT grid (heaviest chunks first), flat%8 = bh%8 XCD pinning.
// Swapped QK^T, in-register softmax, cvt_pk+permlane P-transpose.
// Q pre-scaled by 0.125*log2e (exp2 domain).
__global__ __launch_bounds__(256, 4) void attn_fwd(
    const u16* __restrict__ Q, const u16* __restrict__ Kk,
    const u16* __restrict__ Vt, u16* __restrict__ O)
{
  __shared__ char smem[32768];           // 2 x (K 8K | V 8K)
  const int t = threadIdx.x;
  const int lane = t & 63, wid = t >> 6;
  const int lg = lane >> 4, lc = lane & 15;
  const int flat = blockIdx.x;           // 1024 blocks, LPT order
  const int bh = flat & 63;
  const int qc = 15 - (flat >> 6);       // heaviest (qc=15) first
  const int b = bh >> 4, h = bh & 15;
  const f32x4 fz = {0.f, 0.f, 0.f, 0.f};
  const float THR = 11.5f;               // defer threshold (exp2 domain)
  const bool ev = ((lg & 1) == 0);

  auto STAGE = [&](int buf, int kt) {
    const int kbase = kt << 6;
    char* Kb = smem + buf * 16384;
    char* Vb = Kb + 8192;
#pragma unroll
    for (int p = 0; p < 4; ++p) {
      const int idx = wid * 4 + p;       // 0..15 (8 K-chunks, 8 V-chunks)
      const int rb = (idx & 7) * 8;
      const int row = rb + (lane >> 3);
      const int ce = (((lane & 7) << 4) ^ ((row & 7) << 4)) >> 1;
      if (idx < 8)
        gload16(Kk + ((size_t)bh * 2048 + kbase + row) * 64 + ce, Kb + rb * 128);
      else
        gload16(Vt + ((size_t)bh * 64 + row) * 2048 + kbase + ce, Vb + rb * 128);
    }
  };

  const int qw = qc * 128 + wid * 32;    // wave's first q row

  bf16x8 qf[2][2];                       // [qg][kh]: col=q=qw+qg*16+lc, k=d
#pragma unroll
  for (int qg = 0; qg < 2; ++qg)
#pragma unroll
    for (int kh = 0; kh < 2; ++kh)
      qf[qg][kh] = *(const bf16x8*)(Q + ((size_t)bh * 2048 + qw + qg * 16 + lc) * 64 + kh * 32 + lg * 8);

  f32x4 o[2][4];                         // [qg][dn]  O^T: row=d, col=q
#pragma unroll
  for (int qg = 0; qg < 2; ++qg)
#pragma unroll
    for (int dn = 0; dn < 4; ++dn) o[qg][dn] = fz;
  float mrow[2] = {-1e30f, -1e30f}, lsum[2] = {0.f, 0.f};

  const int nt = 2 * qc + 2;             // 64-kv tiles covering k <= qc*128+127
  STAGE(0, 0);
  __syncthreads();
  for (int kt = 0; kt < nt; ++kt) {
    const int cur = kt & 1;
    if (kt + 1 < nt) STAGE(cur ^ 1, kt + 1);   // prefetch next tile
    const int kbase = kt << 6;
    const char* Ks = smem + cur * 16384;
    const char* Vs = Ks + 8192;
    if (kbase <= qw + 31) {              // wave has unmasked work here
      // --- QK^T (swapped): sfT[nf][qg] row kv=kbase+nf*16+lg*4+j, col q ---
      f32x4 sfT[4][2];
#pragma unroll
      for (int nf = 0; nf < 4; ++nf)
#pragma unroll
        for (int qg = 0; qg < 2; ++qg) sfT[nf][qg] = fz;
      __builtin_amdgcn_s_setprio(1);
#pragma unroll
      for (int kh = 0; kh < 2; ++kh) {
        bf16x8 kb[4];
#pragma unroll
        for (int nf = 0; nf < 4; ++nf) {
          const int r = nf * 16 + lc;
          kb[nf] = *(const bf16x8*)(Ks + r * 128 + ((kh * 64 + (lg << 4)) ^ ((r & 7) << 4)));
        }
#pragma unroll
        for (int nf = 0; nf < 4; ++nf) {
          sfT[nf][0] = mfma16(kb[nf], qf[0][kh], sfT[nf][0]);
          sfT[nf][1] = mfma16(kb[nf], qf[1][kh], sfT[nf][1]);
        }
      }
      __builtin_amdgcn_s_setprio(0);
      // --- causal mask (diagonal-overlap tiles only) ---
      if (kbase + 63 > qw) {
#pragma unroll
        for (int qg = 0; qg < 2; ++qg) {
          const int qq = qw + qg * 16 + lc;
#pragma unroll
          for (int nf = 0; nf < 4; ++nf)
#pragma unroll
            for (int j = 0; j < 4; ++j)
              if (kbase + nf * 16 + (lg << 2) + j > qq) sfT[nf][qg][j] = -1e30f;
        }
      }
      // --- per-lane max + xor16/32 reduce; defer-rescale ---
      float pm[2];
#pragma unroll
      for (int qg = 0; qg < 2; ++qg) {
        float m = sfT[0][qg][0];
#pragma unroll
        for (int nf = 0; nf < 4; ++nf)
#pragma unroll
          for (int j = 0; j < 4; ++j) m = fmaxf(m, sfT[nf][qg][j]);
        m = fmaxf(m, __shfl_xor(m, 16));
        m = fmaxf(m, __shfl_xor(m, 32));
        pm[qg] = m;
      }
      const bool ok = (pm[0] <= mrow[0] + THR) && (pm[1] <= mrow[1] + THR);
      if (!__all(ok)) {
#pragma unroll
        for (int qg = 0; qg < 2; ++qg) {
          const float mn = fmaxf(mrow[qg], pm[qg]);
          const float sc = exp2f(mrow[qg] - mn);
          mrow[qg] = mn;
          lsum[qg] *= sc;
#pragma unroll
          for (int dn = 0; dn < 4; ++dn)
#pragma unroll
            for (int j = 0; j < 4; ++j) o[qg][dn][j] *= sc;
        }
      }
      // --- P = exp2(S - m), in place; accumulate row-sum ---
#pragma unroll
      for (int qg = 0; qg < 2; ++qg)
#pragma unroll
        for (int nf = 0; nf < 4; ++nf)
#pragma unroll
          for (int j = 0; j < 4; ++j) {
            const float p = exp2f(sfT[nf][qg][j] - mrow[qg]);
            sfT[nf][qg][j] = p;
            lsum[qg] += p;
          }
      // --- P^T -> PV B-frag: cvt_pk + permlane32_swap + xor16 ---
      u32 pw[2][2][4];                   // [qg][kh][w]: k = 32kh+8lg+{2w,2w+1}
#pragma unroll
      for (int qg = 0; qg < 2; ++qg)
#pragma unroll
        for (int kh = 0; kh < 2; ++kh) {
          u32 A0 = cvtpk(sfT[2 * kh][qg][0], sfT[2 * kh][qg][1]);
          u32 A1 = cvtpk(sfT[2 * kh][qg][2], sfT[2 * kh][qg][3]);
          u32 B0 = cvtpk(sfT[2 * kh + 1][qg][0], sfT[2 * kh + 1][qg][1]);
          u32 B1 = cvtpk(sfT[2 * kh + 1][qg][2], sfT[2 * kh + 1][qg][3]);
          pswap(A0, B0);                 // A0=[A.lo|B.lo], B0=[A.hi|B.hi]
          pswap(A1, B1);
          const u32 P0s = __shfl_xor(A0, 16);
          const u32 Q0s = __shfl_xor(B0, 16);
          const u32 P1s = __shfl_xor(A1, 16);
          const u32 Q1s = __shfl_xor(B1, 16);
          pw[qg][kh][0] = ev ? A0 : Q0s;
          pw[qg][kh][1] = ev ? A1 : Q1s;
          pw[qg][kh][2] = ev ? P0s : B0;
          pw[qg][kh][3] = ev ? P1s : B1;
        }
      // --- PV: O^T[d][q] += V^T[d][k] * P^T[k][q] ---
      __builtin_amdgcn_s_setprio(1);
#pragma unroll
      for (int kh = 0; kh < 2; ++kh) {
        union { u32 u[4]; bf16x8 v; } p0, p1;
#pragma unroll
        for (int w = 0; w < 4; ++w) { p0.u[w] = pw[0][kh][w]; p1.u[w] = pw[1][kh][w]; }
#pragma unroll
        for (int dn = 0; dn < 4; ++dn) {
          const int vr = dn * 16 + lc;
          const bf16x8 vb = *(const bf16x8*)(Vs + vr * 128 + ((kh * 64 + (lg << 4)) ^ ((vr & 7) << 4)));
          o[0][dn] = mfma16(vb, p0.v, o[0][dn]);
          o[1][dn] = mfma16(vb, p1.v, o[1][dn]);
        }
      }
      __builtin_amdgcn_s_setprio(0);
    }
    __syncthreads();                     // next buffer staged; cur reusable
  }
  // --- epilogue: O[b, s=qw+qg*16+lc, h, d=dn*16+lg*4+j] = o / lsum ---
#pragma unroll
  for (int qg = 0; qg < 2; ++qg) {
    float l = lsum[qg];
    l += __shfl_xor(l, 16);
    l += __shfl_xor(l, 32);
    const float inv = __builtin_amdgcn_rcpf(l);
    const size_t ob = ((size_t)(b * 2048 + qw + qg * 16 + lc) * 16 + h) * 64 + (lg << 2);
#pragma unroll
    for (int dn = 0; dn < 4; ++dn) {
      u16x4 wv;
#pragma unroll
      for (int j = 0; j < 4; ++j) wv[j] = f2b(o[qg][dn][j] * inv);
      *(u16x4*)(O + ob + dn * 16) = wv;
    }
  }
}

// ---------------------------------------------------------------------------
extern "C" void kernel_launch(void* const* d_in, const int* in_sizes, int n_in,
                              void* d_out, int out_size, void* d_ws, size_t ws_size,
                              hipStream_t stream)
{
  (void)in_sizes; (void)n_in; (void)out_size; (void)ws_size;
  const float* xq  = (const float*)d_in[0];
  const float* xk  = (const float*)d_in[1];
  const float* xv  = (const float*)d_in[2];
  // d_in[3] = causal mask -- hardcoded in attn_fwd
  const float* wq1 = (const float*)d_in[4];
  const float* bq1 = (const float*)d_in[5];
  const float* wq2 = (const float*)d_in[6];
  const float* bq2 = (const float*)d_in[7];
  const float* wk1 = (const float*)d_in[8];
  const float* bk1 = (const float*)d_in[9];
  const float* wk2 = (const float*)d_in[10];
  const float* bk2 = (const float*)d_in[11];
  const float* wv1 = (const float*)d_in[12];
  const float* bv1 = (const float*)d_in[13];
  const float* wv2 = (const float*)d_in[14];
  const float* bv2 = (const float*)d_in[15];
  const float* wo  = (const float*)d_in[16];
  const float* bo  = (const float*)d_in[17];

  // Workspace (98.5 MB): WB 14MB | XQ (later XV) | XK (later AO) | QB | KB | VT
  char* ws = (char*)d_ws;
  u16* WB = (u16*)ws;
  u16* XQ = (u16*)(ws + 14680064);
  u16* XK = (u16*)(ws + 31457280);
  u16* QB = (u16*)(ws + 48234496);
  u16* KB = (u16*)(ws + 65011712);
  u16* VT = (u16*)(ws + 81788928);
  u16* XV = XQ;                          // XQ dead after the Q+K swiglu
  u16* AO = XK;                          // XK dead after the Q+K swiglu
  u16* WCQ = WB;
  u16* WCK = WB + 2097152;
  u16* WCV = WB + 4194304;
  u16* WO  = WB + 6291456;

  P6 p6 = {{wq1, wq2, wk1, wk2, wv1, wv2}};
  cvt_wpair<<<dim3(1024, 3), 256, 0, stream>>>(p6, WB);
  cvt_x<<<dim3(512, 1), 256, 0, stream>>>(wo, WO, wo, WO);
  cvt_x<<<dim3(4096, 2), 256, 0, stream>>>(xq, XQ, xk, XK);

  const float QSCALE = 0.125f * 1.44269504088896f;  // 1/sqrt(dk) * log2(e)
  GArgs gq = {XQ, WCQ, bq1, bq2, QB, QSCALE};
  GArgs gk = {XK, WCK, bk1, bk2, KB, 1.0f};
  gemmP<0, true><<<2048, 256, 0, stream>>>(gq, gk);

  cvt_x<<<dim3(4096, 1), 256, 0, stream>>>(xv, XV, xv, XV);
  GArgs gv = {XV, WCV, bv1, bv2, VT, 1.0f};
  gemmP<1, false><<<1024, 256, 0, stream>>>(gv, gv);

  attn_fwd<<<1024, 256, 0, stream>>>(QB, KB, VT, AO);

  GArgs go = {AO, WO, bo, nullptr, d_out, 1.0f};
  gemmP<2, false><<<512, 256, 0, stream>>>(go, go);
}

// Round 15
// 233.944 us; speedup vs baseline: 1.1070x; 1.1070x over previous
//
#include <hip/hip_runtime.h>

// B=4, S=2048, D_MODEL=1024, H=16, DK=64.  M = B*S = 8192.
// mega_cvt (weights Wcat + wo + xq + xk + xv->d_out scratch, ONE launch)
// -> triple gemm128r launch (Q,K swiglu + V swiglu->V^T, 3072 blocks)
// -> causal flash attention (round-10 proven) -> output GEMM (gemm128r).

typedef __bf16 bf16;
typedef bf16 bf16x8 __attribute__((ext_vector_type(8)));
typedef float f32x4 __attribute__((ext_vector_type(4)));
typedef unsigned short u16;
typedef unsigned int u32;
typedef u16 u16x8 __attribute__((ext_vector_type(8)));
typedef u16 u16x4 __attribute__((ext_vector_type(4)));

#define DEVI static __device__ __forceinline__

DEVI u16 f2b(float f) {                    // f32 -> bf16 bits, RNE
  union { float f; u32 u; } v; v.f = f;
  u32 r = v.u + 0x7FFFu + ((v.u >> 16) & 1u);
  return (u16)(r >> 16);
}
DEVI f32x4 mfma16(bf16x8 a, bf16x8 b, f32x4 c) {
  return __builtin_amdgcn_mfma_f32_16x16x32_bf16(a, b, c, 0, 0, 0);
}
DEVI void gload16(const void* g, void* l) {
  __builtin_amdgcn_global_load_lds(
      (const __attribute__((address_space(1))) void*)g,
      (__attribute__((address_space(3))) void*)l, 16, 0, 0);
}
DEVI u32 cvtpk(float lo, float hi) {       // bf16 pair, RNE
  u32 r;
  asm("v_cvt_pk_bf16_f32 %0, %1, %2" : "=v"(r) : "v"(lo), "v"(hi));
  return r;
}
DEVI void pswap(u32& a, u32& b) {          // a' = [a.lo|b.lo], b' = [a.hi|b.hi]
  asm("v_permlane32_swap_b32 %0, %1" : "+v"(a), "+v"(b));
}

// ---------------------------------------------------------------------------
// mega_cvt: ONE launch for all f32->bf16 conversions.
//   blocks [0,3072)      : Wcat build (3 pairs; per pair [2048,1024] bf16,
//                          tile-row t7 of each 128-row block -> gate g=(t7>>4)&1,
//                          col (t7>>5)*16+(t7&15))
//   blocks [3072,3584)   : wo  (1024x1024)
//   blocks [3584,7680)   : xq  (8192x1024)
//   blocks [7680,11776)  : xk
//   blocks [11776,15872) : xv -> XV (d_out scratch)
struct CvtArgs {
  const float* w[6];
  const float* wo; const float* xq; const float* xk; const float* xv;
  u16* WB; u16* WO; u16* XQ; u16* XK; u16* XV;
};

DEVI void cvt8(const float* __restrict__ src, u16* __restrict__ dst, int i) {
  const f32x4 a = ((const f32x4*)src)[i * 2];
  const f32x4 b = ((const f32x4*)src)[i * 2 + 1];
  u16x8 w;
#pragma unroll
  for (int j = 0; j < 4; ++j) { w[j] = f2b(a[j]); w[4 + j] = f2b(b[j]); }
  ((u16x8*)dst)[i] = w;
}

__global__ void mega_cvt(CvtArgs a) {
  const int blk = blockIdx.x, t = threadIdx.x;
  if (blk < 3072) {                           // Wcat build
    const int pair = blk >> 10;
    const int i = (blk & 1023) * 256 + t;
    const float* w1 = a.w[2 * pair];
    const float* w2 = a.w[2 * pair + 1];
    u16* dst = a.WB + (size_t)pair * 2097152;
    const int v = i >> 7;                     // Wcat row 0..2047
    const int k0 = (i & 127) << 3;
    const int t7 = v & 127;
    const int g = (t7 >> 4) & 1;
    const int c = (v >> 7) * 64 + ((t7 >> 5) << 4) + (t7 & 15);
    const float* src = (g ? w2 : w1) + (size_t)c * 1024 + k0;
    const f32x4 x = *(const f32x4*)src;
    const f32x4 y = *(const f32x4*)(src + 4);
    u16x8 wv;
#pragma unroll
    for (int j = 0; j < 4; ++j) { wv[j] = f2b(x[j]); wv[4 + j] = f2b(y[j]); }
    *(u16x8*)(dst + (size_t)v * 1024 + k0) = wv;
  } else if (blk < 3584) {
    cvt8(a.wo, a.WO, (blk - 3072) * 256 + t);
  } else if (blk < 7680) {
    cvt8(a.xq, a.XQ, (blk - 3584) * 256 + t);
  } else if (blk < 11776) {
    cvt8(a.xk, a.XK, (blk - 7680) * 256 + t);
  } else {
    cvt8(a.xv, a.XV, (blk - 11776) * 256 + t);
  }
}

// ---------------------------------------------------------------------------
// gemm128r: 128x128 GEMM (m97 structure, round-10 proven), BK=64, 256 thr
// (4 waves 2x2 of 64x64), static 64 KB LDS dbuf -> 2 blocks/CU,
// global_load_lds, 1 barrier/K-step.  Runtime-mode epilogue:
//   mode 0: dual-gate swiglu -> Q/K [B,H,S,64] (scale folded)
//   mode 1: dual-gate swiglu -> V^T [B,H,64,S]
//   mode 2: plain + bias -> f32 [8192,1024]
// Triple launch: fl<1024 -> g0, <2048 -> g1, else g2 (tails overlap).
// fl%8 == (fl&1023)%8 -> XCD panel pinning preserved.
struct GArgs {
  const u16* A; const u16* W;
  const float* b1; const float* b2;
  void* out; float scale; int mode;
};

template<int NXB>
__global__ __launch_bounds__(256, 2) void gemm128r(GArgs g0, GArgs g1, GArgs g2)
{
  __shared__ char smem[65536];                 // 2 x (As 16K | Bs 16K)
  const int fl = blockIdx.x;
  const GArgs g = (fl >= 2048) ? g2 : ((fl >= 1024) ? g1 : g0);
  const int local = fl & 1023;
  const int t = threadIdx.x;
  const int lane = t & 63, wid = t >> 6;
  const int lg = lane >> 4, lc = lane & 15;
  const int wr = (wid >> 1) * 64, wc = (wid & 1) * 64;
  const int xcd = local & 7, w8 = local >> 3;
  const int m0 = (xcd * 8 + w8 / NXB) * 128;   // same-m blocks share XCD
  const int bx = w8 % NXB;
  const int K = 1024;
  const int srow = lane >> 3, scolb = (lane & 7) << 4;

  const f32x4 fz = {0.f, 0.f, 0.f, 0.f};
  f32x4 acc[4][4];
#pragma unroll
  for (int i = 0; i < 4; ++i)
#pragma unroll
    for (int j = 0; j < 4; ++j) acc[i][j] = fz;

  auto STAGE = [&](int buf, int kt) {
    const int k0 = kt << 6;
    char* As = smem + buf * 32768;
    char* Ws = As + 16384;
#pragma unroll
    for (int p = 0; p < 4; ++p) {
      const int rb = wid * 32 + p * 8;         // wave-uniform chunk base
      const int row = rb + srow;
      const int ce = (scolb ^ ((row & 7) << 4)) >> 1;
      gload16(g.A + (size_t)(m0 + row) * K + k0 + ce, As + rb * 128);
      gload16(g.W + (size_t)(bx * 128 + row) * K + k0 + ce, Ws + rb * 128);
    }
  };

  STAGE(0, 0);
  __syncthreads();
  for (int kt = 0; kt < 16; ++kt) {
    const int cur = kt & 1;
    if (kt < 15) STAGE(cur ^ 1, kt + 1);       // issue next tile early
    const char* As = smem + cur * 32768;
    const char* Ws = As + 16384;
#pragma unroll
    for (int kh = 0; kh < 2; ++kh) {
      bf16x8 af[4], bfr[4];
#pragma unroll
      for (int mf = 0; mf < 4; ++mf) {
        const int r = wr + mf * 16 + lc;
        af[mf] = *(const bf16x8*)(As + r * 128 + ((kh * 64 + (lg << 4)) ^ ((r & 7) << 4)));
      }
#pragma unroll
      for (int nf = 0; nf < 4; ++nf) {
        const int v = wc + nf * 16 + lc;
        bfr[nf] = *(const bf16x8*)(Ws + v * 128 + ((kh * 64 + (lg << 4)) ^ ((v & 7) << 4)));
      }
#pragma unroll
      for (int mf = 0; mf < 4; ++mf)
#pragma unroll
        for (int nf = 0; nf < 4; ++nf)
          acc[mf][nf] = mfma16(af[mf], bfr[nf], acc[mf][nf]);
    }
    __syncthreads();                           // next buffer ready
  }
  // ---- runtime-mode epilogue (mappings verbatim round 10) ----
  if (g.mode == 2) {
    float* Co = (float*)g.out;
#pragma unroll
    for (int mf = 0; mf < 4; ++mf)
#pragma unroll
      for (int nf = 0; nf < 4; ++nf) {
        const int r0 = m0 + wr + mf * 16 + (lg << 2);
        const int C = bx * 128 + wc + nf * 16 + lc;
        const float bv = g.b1[C];
#pragma unroll
        for (int j = 0; j < 4; ++j)
          Co[(size_t)(r0 + j) * 1024 + C] = acc[mf][nf][j] + bv;
      }
  } else {
    u16* Co = (u16*)g.out;
#pragma unroll
    for (int mf = 0; mf < 4; ++mf) {
      const int r0 = m0 + wr + mf * 16 + (lg << 2);
#pragma unroll
      for (int p = 0; p < 2; ++p) {            // acc pairs (2p, 2p+1) = (G1,G2)
        const int C = bx * 64 + (wid & 1) * 32 + p * 16 + lc;
        const float b1v = g.b1[C], b2v = g.b2[C];
        const int h = C >> 6, d = C & 63;
        if (g.mode == 0) {
#pragma unroll
          for (int j = 0; j < 4; ++j) {
            const int r = r0 + j;
            const float x = acc[mf][2 * p][j] + b1v;
            const float y = acc[mf][2 * p + 1][j] + b2v;
            const float vv = (x / (1.f + __expf(-x))) * y * g.scale;
            const int bb = r >> 11, s = r & 2047;
            Co[((size_t)(bb * 16 + h) * 2048 + s) * 64 + d] = f2b(vv);
          }
        } else {
          u16x4 wv;
#pragma unroll
          for (int j = 0; j < 4; ++j) {
            const float x = acc[mf][2 * p][j] + b1v;
            const float y = acc[mf][2 * p + 1][j] + b2v;
            wv[j] = f2b((x / (1.f + __expf(-x))) * y);
          }
          const int bb = r0 >> 11, s0 = r0 & 2047;   // r0 % 4 == 0
          *(u16x4*)(Co + ((size_t)(bb * 16 + h) * 64 + d) * 2048 + s0) = wv;
        }
      }
    }
  }
}

// ---------------------------------------------------------------------------
// Causal flash attention (round-10 proven).  LDS-staged K/V (dbuf
// global_load_lds, 1 barrier/tile), 4 waves x 32 q/wave = 128 q/block,
// 1024-block LPT grid (heaviest chunks first), flat%8 = bh%8 XCD pinning.
// Swapped QK^T, in-register softmax, cvt_pk+permlane P-transpose.
// Q pre-scaled by 0.125*log2e (exp2 domain).
__global__ __launch_bounds__(256, 4) void attn_fwd(
    const u16* __restrict__ Q, const u16* __restrict__ Kk,
    const u16* __restrict__ Vt, u16* __restrict__ O)
{
  __shared__ char smem[32768];           // 2 x (K 8K | V 8K)
  const int t = threadIdx.x;
  const int lane = t & 63, wid = t >> 6;
  const int lg = lane >> 4, lc = lane & 15;
  const int flat = blockIdx.x;           // 1024 blocks, LPT order
  const int bh = flat & 63;
  const int qc = 15 - (flat >> 6);       // heaviest (qc=15) first
  const int b = bh >> 4, h = bh & 15;
  const f32x4 fz = {0.f, 0.f, 0.f, 0.f};
  const float THR = 11.5f;               // defer threshold (exp2 domain)
  const bool ev = ((lg & 1) == 0);

  auto STAGE = [&](int buf, int kt) {
    const int kbase = kt << 6;
    char* Kb = smem + buf * 16384;
    char* Vb = Kb + 8192;
#pragma unroll
    for (int p = 0; p < 4; ++p) {
      const int idx = wid * 4 + p;       // 0..15 (8 K-chunks, 8 V-chunks)
      const int rb = (idx & 7) * 8;
      const int row = rb + (lane >> 3);
      const int ce = (((lane & 7) << 4) ^ ((row & 7) << 4)) >> 1;
      if (idx < 8)
        gload16(Kk + ((size_t)bh * 2048 + kbase + row) * 64 + ce, Kb + rb * 128);
      else
        gload16(Vt + ((size_t)bh * 64 + row) * 2048 + kbase + ce, Vb + rb * 128);
    }
  };

  const int qw = qc * 128 + wid * 32;    // wave's first q row

  bf16x8 qf[2][2];                       // [qg][kh]: col=q=qw+qg*16+lc, k=d
#pragma unroll
  for (int qg = 0; qg < 2; ++qg)
#pragma unroll
    for (int kh = 0; kh < 2; ++kh)
      qf[qg][kh] = *(const bf16x8*)(Q + ((size_t)bh * 2048 + qw + qg * 16 + lc) * 64 + kh * 32 + lg * 8);

  f32x4 o[2][4];                         // [qg][dn]  O^T: row=d, col=q
#pragma unroll
  for (int qg = 0; qg < 2; ++qg)
#pragma unroll
    for (int dn = 0; dn < 4; ++dn) o[qg][dn] = fz;
  float mrow[2] = {-1e30f, -1e30f}, lsum[2] = {0.f, 0.f};

  const int nt = 2 * qc + 2;             // 64-kv tiles covering k <= qc*128+127
  STAGE(0, 0);
  __syncthreads();
  for (int kt = 0; kt < nt; ++kt) {
    const int cur = kt & 1;
    if (kt + 1 < nt) STAGE(cur ^ 1, kt + 1);   // prefetch next tile
    const int kbase = kt << 6;
    const char* Ks = smem + cur * 16384;
    const char* Vs = Ks + 8192;
    if (kbase <= qw + 31) {              // wave has unmasked work here
      // --- QK^T (swapped): sfT[nf][qg] row kv=kbase+nf*16+lg*4+j, col q ---
      f32x4 sfT[4][2];
#pragma unroll
      for (int nf = 0; nf < 4; ++nf)
#pragma unroll
        for (int qg = 0; qg < 2; ++qg) sfT[nf][qg] = fz;
      __builtin_amdgcn_s_setprio(1);
#pragma unroll
      for (int kh = 0; kh < 2; ++kh) {
        bf16x8 kb[4];
#pragma unroll
        for (int nf = 0; nf < 4; ++nf) {
          const int r = nf * 16 + lc;
          kb[nf] = *(const bf16x8*)(Ks + r * 128 + ((kh * 64 + (lg << 4)) ^ ((r & 7) << 4)));
        }
#pragma unroll
        for (int nf = 0; nf < 4; ++nf) {
          sfT[nf][0] = mfma16(kb[nf], qf[0][kh], sfT[nf][0]);
          sfT[nf][1] = mfma16(kb[nf], qf[1][kh], sfT[nf][1]);
        }
      }
      __builtin_amdgcn_s_setprio(0);
      // --- causal mask (diagonal-overlap tiles only) ---
      if (kbase + 63 > qw) {
#pragma unroll
        for (int qg = 0; qg < 2; ++qg) {
          const int qq = qw + qg * 16 + lc;
#pragma unroll
          for (int nf = 0; nf < 4; ++nf)
#pragma unroll
            for (int j = 0; j < 4; ++j)
              if (kbase + nf * 16 + (lg << 2) + j > qq) sfT[nf][qg][j] = -1e30f;
        }
      }
      // --- per-lane max + xor16/32 reduce; defer-rescale ---
      float pm[2];
#pragma unroll
      for (int qg = 0; qg < 2; ++qg) {
        float m = sfT[0][qg][0];
#pragma unroll
        for (int nf = 0; nf < 4; ++nf)
#pragma unroll
          for (int j = 0; j < 4; ++j) m = fmaxf(m, sfT[nf][qg][j]);
        m = fmaxf(m, __shfl_xor(m, 16));
        m = fmaxf(m, __shfl_xor(m, 32));
        pm[qg] = m;
      }
      const bool ok = (pm[0] <= mrow[0] + THR) && (pm[1] <= mrow[1] + THR);
      if (!__all(ok)) {
#pragma unroll
        for (int qg = 0; qg < 2; ++qg) {
          const float mn = fmaxf(mrow[qg], pm[qg]);
          const float sc = exp2f(mrow[qg] - mn);
          mrow[qg] = mn;
          lsum[qg] *= sc;
#pragma unroll
          for (int dn = 0; dn < 4; ++dn)
#pragma unroll
            for (int j = 0; j < 4; ++j) o[qg][dn][j] *= sc;
        }
      }
      // --- P = exp2(S - m), in place; accumulate row-sum ---
#pragma unroll
      for (int qg = 0; qg < 2; ++qg)
#pragma unroll
        for (int nf = 0; nf < 4; ++nf)
#pragma unroll
          for (int j = 0; j < 4; ++j) {
            const float p = exp2f(sfT[nf][qg][j] - mrow[qg]);
            sfT[nf][qg][j] = p;
            lsum[qg] += p;
          }
      // --- P^T -> PV B-frag: cvt_pk + permlane32_swap + xor16 ---
      u32 pw[2][2][4];                   // [qg][kh][w]: k = 32kh+8lg+{2w,2w+1}
#pragma unroll
      for (int qg = 0; qg < 2; ++qg)
#pragma unroll
        for (int kh = 0; kh < 2; ++kh) {
          u32 A0 = cvtpk(sfT[2 * kh][qg][0], sfT[2 * kh][qg][1]);
          u32 A1 = cvtpk(sfT[2 * kh][qg][2], sfT[2 * kh][qg][3]);
          u32 B0 = cvtpk(sfT[2 * kh + 1][qg][0], sfT[2 * kh + 1][qg][1]);
          u32 B1 = cvtpk(sfT[2 * kh + 1][qg][2], sfT[2 * kh + 1][qg][3]);
          pswap(A0, B0);                 // A0=[A.lo|B.lo], B0=[A.hi|B.hi]
          pswap(A1, B1);
          const u32 P0s = __shfl_xor(A0, 16);
          const u32 Q0s = __shfl_xor(B0, 16);
          const u32 P1s = __shfl_xor(A1, 16);
          const u32 Q1s = __shfl_xor(B1, 16);
          pw[qg][kh][0] = ev ? A0 : Q0s;
          pw[qg][kh][1] = ev ? A1 : Q1s;
          pw[qg][kh][2] = ev ? P0s : B0;
          pw[qg][kh][3] = ev ? P1s : B1;
        }
      // --- PV: O^T[d][q] += V^T[d][k] * P^T[k][q] ---
      __builtin_amdgcn_s_setprio(1);
#pragma unroll
      for (int kh = 0; kh < 2; ++kh) {
        union { u32 u[4]; bf16x8 v; } p0, p1;
#pragma unroll
        for (int w = 0; w < 4; ++w) { p0.u[w] = pw[0][kh][w]; p1.u[w] = pw[1][kh][w]; }
#pragma unroll
        for (int dn = 0; dn < 4; ++dn) {
          const int vr = dn * 16 + lc;
          const bf16x8 vb = *(const bf16x8*)(Vs + vr * 128 + ((kh * 64 + (lg << 4)) ^ ((vr & 7) << 4)));
          o[0][dn] = mfma16(vb, p0.v, o[0][dn]);
          o[1][dn] = mfma16(vb, p1.v, o[1][dn]);
        }
      }
      __builtin_amdgcn_s_setprio(0);
    }
    __syncthreads();                     // next buffer staged; cur reusable
  }
  // --- epilogue: O[b, s=qw+qg*16+lc, h, d=dn*16+lg*4+j] = o / lsum ---
#pragma unroll
  for (int qg = 0; qg < 2; ++qg) {
    float l = lsum[qg];
    l += __shfl_xor(l, 16);
    l += __shfl_xor(l, 32);
    const float inv = __builtin_amdgcn_rcpf(l);
    const size_t ob = ((size_t)(b * 2048 + qw + qg * 16 + lc) * 16 + h) * 64 + (lg << 2);
#pragma unroll
    for (int dn = 0; dn < 4; ++dn) {
      u16x4 wv;
#pragma unroll
      for (int j = 0; j < 4; ++j) wv[j] = f2b(o[qg][dn][j] * inv);
      *(u16x4*)(O + ob + dn * 16) = wv;
    }
  }
}

// ---------------------------------------------------------------------------
extern "C" void kernel_launch(void* const* d_in, const int* in_sizes, int n_in,
                              void* d_out, int out_size, void* d_ws, size_t ws_size,
                              hipStream_t stream)
{
  (void)in_sizes; (void)n_in; (void)out_size; (void)ws_size;
  const float* xq  = (const float*)d_in[0];
  const float* xk  = (const float*)d_in[1];
  const float* xv  = (const float*)d_in[2];
  // d_in[3] = causal mask -- hardcoded in attn_fwd
  const float* wq1 = (const float*)d_in[4];
  const float* bq1 = (const float*)d_in[5];
  const float* wq2 = (const float*)d_in[6];
  const float* bq2 = (const float*)d_in[7];
  const float* wk1 = (const float*)d_in[8];
  const float* bk1 = (const float*)d_in[9];
  const float* wk2 = (const float*)d_in[10];
  const float* bk2 = (const float*)d_in[11];
  const float* wv1 = (const float*)d_in[12];
  const float* bv1 = (const float*)d_in[13];
  const float* wv2 = (const float*)d_in[14];
  const float* bv2 = (const float*)d_in[15];
  const float* wo  = (const float*)d_in[16];
  const float* bo  = (const float*)d_in[17];

  // Workspace (98.5 MB): WB 14MB | XQ | XK (later AO) | QB | KB | VT
  // XV lives in d_out (33.5 MB f32, only needs final values at the end).
  char* ws = (char*)d_ws;
  u16* WB = (u16*)ws;
  u16* XQ = (u16*)(ws + 14680064);
  u16* XK = (u16*)(ws + 31457280);
  u16* QB = (u16*)(ws + 48234496);
  u16* KB = (u16*)(ws + 65011712);
  u16* VT = (u16*)(ws + 81788928);
  u16* XV = (u16*)d_out;                 // d_out as scratch until out-GEMM
  u16* AO = XK;                          // XK dead after the triple gemm
  u16* WCQ = WB;
  u16* WCK = WB + 2097152;
  u16* WCV = WB + 4194304;
  u16* WO  = WB + 6291456;

  CvtArgs ca;
  ca.w[0] = wq1; ca.w[1] = wq2; ca.w[2] = wk1;
  ca.w[3] = wk2; ca.w[4] = wv1; ca.w[5] = wv2;
  ca.wo = wo; ca.xq = xq; ca.xk = xk; ca.xv = xv;
  ca.WB = WB; ca.WO = WO; ca.XQ = XQ; ca.XK = XK; ca.XV = XV;
  mega_cvt<<<15872, 256, 0, stream>>>(ca);

  const float QSCALE = 0.125f * 1.44269504088896f;  // 1/sqrt(dk) * log2(e)
  GArgs gq = {XQ, WCQ, bq1, bq2, QB, QSCALE, 0};
  GArgs gk = {XK, WCK, bk1, bk2, KB, 1.0f,   0};
  GArgs gv = {XV, WCV, bv1, bv2, VT, 1.0f,   1};
  gemm128r<16><<<3072, 256, 0, stream>>>(gq, gk, gv);

  attn_fwd<<<1024, 256, 0, stream>>>(QB, KB, VT, AO);

  GArgs go = {AO, WO, bo, nullptr, d_out, 1.0f, 2};
  gemm128r<8><<<512, 256, 0, stream>>>(go, go, go);
}